// Round 9
// baseline (156.713 us; speedup 1.0000x reference)
//
#include <hip/hip_runtime.h>

// DiffVolumeV2: out[b][c][d][h][x] = left[b][c][h][x] - right[b][c][h][clip(4x-d+1, 0, Wr-1)]
// B=4, C=32, H=80, Wl=160, Wr=640, D=48. 314.6 MB out + 32.8 MB in.
//
// R1 72.5 | R2 117 | R3 69.5 | R4 71.9 | R6 66.4 (best: R3+nt) | R7 167 (dense
// grid-stride sweep: k-drift blew the read set, FETCH 269MB) | R8 68.5 (XCD swizzle
// on R6: write-order at that granularity exonerated).
// R9: dense writes done RIGHT. One block = one (bc,d) plane = 51.2KB contiguous
// stores; no LDS, no barrier, direct L2-hot reads. XCD-chunk swizzle pins each
// bc's 48 planes to one XCD => per-XCD read set ~1.5MB << 4MB L2 (drift bounded
// by residency, unlike R7's 16-deep k-loop). tid%40 invariant => gather offsets
// are per-thread constants; body = 1 fx4 load + 4 scalar gathers + 1 nt store.

typedef float fx4 __attribute__((ext_vector_type(4)));

constexpr int Bc  = 4;
constexpr int Cc  = 32;
constexpr int Hc  = 80;
constexpr int WLc = 160;
constexpr int WRc = 640;
constexpr int Dc  = 48;

constexpr int TPBP   = 320;              // 5 waves; 3200 fx4 per plane = 10 iters exactly
constexpr int NBLKP  = Bc * Cc * Dc;     // 6144 plane-blocks
constexpr int NXCD   = 8;
constexpr int CHUNK  = NBLKP / NXCD;     // 768 = 16 bc per XCD chunk

__global__ __launch_bounds__(TPBP) void diffvol48_plane(
    const float* __restrict__ left, const float* __restrict__ right,
    float* __restrict__ out)
{
    // Chunked XCD swizzle: XCD k owns blk in [k*768, (k+1)*768) => each bc's
    // 48 d-planes (and its left/right input) live on exactly one XCD's L2.
    const int wg  = blockIdx.x;
    const int blk = (wg % NXCD) * CHUNK + wg / NXCD;

    const int d  = blk % Dc;
    const int bc = blk / Dc;

    const int tid = threadIdx.x;
    const int x4  = tid % 40;            // invariant across iters (320 ≡ 0 mod 40)
    const int h0  = tid / 40;            // 0..7; h = h0 + 8k

    // Per-thread constant gather offsets within a right row.
    int rofs[4];
    #pragma unroll
    for (int j = 0; j < 4; ++j) {
        int c = 16 * x4 + 4 * j + 1 - d;     // max 637 < 639: upper clip unreachable
        rofs[j] = c < 0 ? 0 : c;
    }

    const float* lptr = left  + (size_t)bc * (Hc * WLc) + h0 * WLc + x4 * 4;
    const float* rptr = right + (size_t)bc * (Hc * WRc) + h0 * WRc;
    float*       optr = out   + (size_t)blk * (Hc * WLc) + tid * 4;

    #pragma unroll
    for (int k = 0; k < 10; ++k) {
        const fx4 lv = *(const fx4*)lptr;        // L2-hot: reused by this bc's 48 planes
        fx4 v;
        #pragma unroll
        for (int j = 0; j < 4; ++j)
            v[j] = lv[j] - rptr[rofs[j]];        // L2-hot gather, 16B lane stride
        __builtin_nontemporal_store(v, (fx4*)optr);   // dense: plane is 51.2KB contiguous
        lptr += 8 * WLc;
        rptr += 8 * WRc;
        optr += TPBP * 4;
    }
}

// Generic fallback (any D) — proven R6 kernel.
constexpr int TPB = 256;
constexpr int RPAD = WRc + WRc / 32;
__global__ __launch_bounds__(TPB) void diffvol_generic(
    const float* __restrict__ left, const float* __restrict__ right,
    float* __restrict__ out, int D)
{
    __shared__ __align__(16) float lrow[WLc];
    __shared__ float rrow[RPAD];

    const int blk = blockIdx.x;
    const int h   = blk % Hc;
    const int bc  = blk / Hc;
    const float* lp = left  + ((size_t)bc * Hc + h) * WLc;
    const float* rp = right + ((size_t)bc * Hc + h) * WRc;
    const int tid = threadIdx.x;

    if (tid < WLc) lrow[tid] = lp[tid];
    for (int i = tid; i < WRc; i += TPB) rrow[i + (i >> 5)] = rp[i];
    __syncthreads();

    float* ob = out + ((size_t)bc * D * Hc + h) * WLc;
    const int total = D * (WLc / 4);
    for (int t = tid; t < total; t += TPB) {
        const int d  = t / (WLc / 4);
        const int g  = t - d * (WLc / 4);
        const int x0 = g * 4;
        const fx4 lv = *(const fx4*)(lrow + x0);
        fx4 v;
        #pragma unroll
        for (int j = 0; j < 4; ++j) {
            int r = 4 * (x0 + j) - d + 1;
            r = r < 0 ? 0 : r;
            v[j] = lv[j] - rrow[r + (r >> 5)];
        }
        __builtin_nontemporal_store(v, (fx4*)(ob + (size_t)d * (Hc * WLc) + x0));
    }
}

extern "C" void kernel_launch(void* const* d_in, const int* in_sizes, int n_in,
                              void* d_out, int out_size, void* d_ws, size_t ws_size,
                              hipStream_t stream) {
    const float* left  = (const float*)d_in[0];
    const float* right = (const float*)d_in[1];
    float* out = (float*)d_out;

    const int D = out_size / (Bc * Cc * Hc * WLc);

    if (D == 48) {
        diffvol48_plane<<<dim3(NBLKP), TPBP, 0, stream>>>(left, right, out);
    } else {
        dim3 grid(Bc * Cc * Hc);
        diffvol_generic<<<grid, TPB, 0, stream>>>(left, right, out, D);
    }
}

// Round 10
// 65.453 us; speedup vs baseline: 2.3943x; 2.3943x over previous
//
#include <hip/hip_runtime.h>

// DiffVolumeV2: out[b][c][d][h][x] = left[b][c][h][x] - right[b][c][h][clip(4x-d+1, 0, Wr-1)]
// B=4, C=32, H=80, Wl=160, Wr=640, D=48. 314.6 MB out + 32.8 MB in.
//
// R1 72.5 | R2 117 | R3 69.5 | R4 71.9 | R6 66.4 (R3+nt, best) | R7 167 | R8 68.5
// | R9 157 (plane-blocks, direct L2 gather: FETCH ideal but ~64 L2 line-txns per
// gather instr => gather MUST be LDS-served; global-gather family is dead).
// R10: R6 family, fixed-(g,dbase) threads. TPB=320 = 8 dbase x 40 g; each thread
// walks d = dbase+8k, k=0..5 (8x6=48 exactly):
//  - left: ONE direct global fx4 load per thread (no lrow staging; wave coalescer
//    dedups the 8x duplicate lines) -- plain load so L2 serves waves 1..4.
//  - slot body: 4x(add,max,pad,ds_read_b32) + 4 sub + 1 nt fx4 store; e -= 8.
//  - right staging + i+(i>>5) padding + nt unchanged (proven). Grid 10240 (proven).

typedef float fx4 __attribute__((ext_vector_type(4)));

constexpr int Bc  = 4;
constexpr int Cc  = 32;
constexpr int Hc  = 80;
constexpr int WLc = 160;
constexpr int WRc = 640;
constexpr int Dc  = 48;
constexpr int TPB = 320;                 // 8 dbase slots x 40 g groups = 5 waves
constexpr int RPAD = WRc + WRc / 32;     // 660: addr = i + (i>>5) kills stride-16 conflicts
constexpr int NBLK = Bc * Cc * Hc;       // 10240

__global__ __launch_bounds__(TPB) void diffvol48(
    const float* __restrict__ left, const float* __restrict__ right,
    float* __restrict__ out)
{
    __shared__ float rrow[RPAD];

    const int blk = blockIdx.x;          // bc*80 + h
    const int h   = blk % Hc;
    const int bc  = blk / Hc;
    const float* lp = left  + ((size_t)bc * Hc + h) * WLc;
    const float* rp = right + ((size_t)bc * Hc + h) * WRc;
    const int tid = threadIdx.x;

    // Stage right row: 160 fx4 nt loads -> padded scalar LDS writes (row is
    // exclusive to this block => no-allocate hint is free).
    if (tid < WRc / 4) {
        fx4 v = __builtin_nontemporal_load((const fx4*)(rp + tid * 4));
        #pragma unroll
        for (int k = 0; k < 4; ++k) { int c = tid * 4 + k; rrow[c + (c >> 5)] = v[k]; }
    }

    // Fixed per-thread coords: g = x-group, dbase = d residue; d = dbase + 8k.
    const int g     = tid % 40;
    const int dbase = tid / 40;          // 0..7

    // Left fragment: direct global load (plain, L2-temporal: 5 waves share lines).
    const fx4 lv = *(const fx4*)(lp + g * 4);

    int e = 16 * g + 1 - dbase;          // c_j = e + 4j; e -= 8 per slot
    float* op = out + (size_t)bc * (Dc * Hc * WLc) + (size_t)dbase * (Hc * WLc)
                    + h * WLc + g * 4;

    __syncthreads();

    #pragma unroll
    for (int k = 0; k < 6; ++k) {        // d = dbase + 8k
        fx4 v;
        #pragma unroll
        for (int j = 0; j < 4; ++j) {
            int c = e + 4 * j;           // max 637 < 639: upper clip unreachable
            c = c < 0 ? 0 : c;           // lower clip -> rrow[0]
            v[j] = lv[j] - rrow[c + (c >> 5)];
        }
        __builtin_nontemporal_store(v, (fx4*)op);
        e  -= 8;
        op += 8 * (Hc * WLc);
    }
}

// Generic fallback (any D) — proven R6 kernel.
constexpr int TPBG = 256;
__global__ __launch_bounds__(TPBG) void diffvol_generic(
    const float* __restrict__ left, const float* __restrict__ right,
    float* __restrict__ out, int D)
{
    __shared__ __align__(16) float lrow[WLc];
    __shared__ float rrow[RPAD];

    const int blk = blockIdx.x;
    const int h   = blk % Hc;
    const int bc  = blk / Hc;
    const float* lp = left  + ((size_t)bc * Hc + h) * WLc;
    const float* rp = right + ((size_t)bc * Hc + h) * WRc;
    const int tid = threadIdx.x;

    if (tid < WLc) lrow[tid] = lp[tid];
    for (int i = tid; i < WRc; i += TPBG) rrow[i + (i >> 5)] = rp[i];
    __syncthreads();

    float* ob = out + ((size_t)bc * D * Hc + h) * WLc;
    const int total = D * (WLc / 4);
    for (int t = tid; t < total; t += TPBG) {
        const int d  = t / (WLc / 4);
        const int g  = t - d * (WLc / 4);
        const int x0 = g * 4;
        const fx4 lv = *(const fx4*)(lrow + x0);
        fx4 v;
        #pragma unroll
        for (int j = 0; j < 4; ++j) {
            int r = 4 * (x0 + j) - d + 1;
            r = r < 0 ? 0 : r;
            v[j] = lv[j] - rrow[r + (r >> 5)];
        }
        __builtin_nontemporal_store(v, (fx4*)(ob + (size_t)d * (Hc * WLc) + x0));
    }
}

extern "C" void kernel_launch(void* const* d_in, const int* in_sizes, int n_in,
                              void* d_out, int out_size, void* d_ws, size_t ws_size,
                              hipStream_t stream) {
    const float* left  = (const float*)d_in[0];
    const float* right = (const float*)d_in[1];
    float* out = (float*)d_out;

    const int D = out_size / (Bc * Cc * Hc * WLc);

    if (D == 48) {
        diffvol48<<<dim3(NBLK), TPB, 0, stream>>>(left, right, out);
    } else {
        dim3 grid(Bc * Cc * Hc);
        diffvol_generic<<<grid, TPBG, 0, stream>>>(left, right, out, D);
    }
}